// Round 13
// baseline (287.233 us; speedup 1.0000x reference)
//
#include <hip/hip_runtime.h>
#include <hip/hip_bf16.h>

#define DIM 128
#define N_GRAPHS 64
#define SSTR 136  // LDS row stride in shorts (272 B)

typedef __attribute__((ext_vector_type(4))) float f32x4;
typedef __attribute__((ext_vector_type(8))) short s16x8;

// ---------------- bf16 helpers (hardware cvt) ----------------

__device__ __forceinline__ short bf16h(float f) {
    return __builtin_bit_cast(short, __float2bfloat16(f));  // HW RTNE cvt
}
__device__ __forceinline__ float bf16f(unsigned short h) {
    unsigned u = ((unsigned)h) << 16;
    return __builtin_bit_cast(float, u);
}

// ---------------- degree / CSR precompute ----------------
// one atomic pass: cnt accumulates degree, returned value is the edge's rank
__global__ void k_rank4(const int4* __restrict__ col4, int* __restrict__ cnt,
                        int4* __restrict__ pos4, int e4) {
    int i = blockIdx.x * blockDim.x + threadIdx.x;
    if (i >= e4) return;
    int4 c = col4[i];
    int4 p;
    p.x = atomicAdd(&cnt[c.x], 1);
    p.y = atomicAdd(&cnt[c.y], 1);
    p.z = atomicAdd(&cnt[c.z], 1);
    p.w = atomicAdd(&cnt[c.w], 1);
    pos4[i] = p;  // coalesced 16B store
}

__global__ __launch_bounds__(256) void k_bsum(const int* __restrict__ cnt,
                                              int* __restrict__ bsum, int n) {
    __shared__ int s[256];
    int t = threadIdx.x;
    int i = blockIdx.x * 256 + t;
    s[t] = (i < n) ? cnt[i] : 0;
    __syncthreads();
    for (int o = 128; o > 0; o >>= 1) {
        if (t < o) s[t] += s[t + o];
        __syncthreads();
    }
    if (t == 0) bsum[blockIdx.x] = s[0];
}

__global__ __launch_bounds__(256) void k_bscan(const int* __restrict__ bsum,
                                               int* __restrict__ bbase, int nb) {
    __shared__ int s[256];
    int t = threadIdx.x;
    int v = (t < nb) ? bsum[t] : 0;
    s[t] = v;
    __syncthreads();
    for (int o = 1; o < 256; o <<= 1) {
        int u = (t >= o) ? s[t - o] : 0;
        __syncthreads();
        s[t] += u;
        __syncthreads();
    }
    if (t < nb) bbase[t] = s[t] - v;  // exclusive
}

// rowptr + dis = rsqrt(1 + degree)
__global__ __launch_bounds__(256) void k_bfinal(const int* __restrict__ cnt,
        const int* __restrict__ bbase, int* __restrict__ rowptr,
        float* __restrict__ dis, int n, int e) {
    __shared__ int s[256];
    int t = threadIdx.x;
    int i = blockIdx.x * 256 + t;
    int v = (i < n) ? cnt[i] : 0;
    s[t] = v;
    __syncthreads();
    for (int o = 1; o < 256; o <<= 1) {
        int u = (t >= o) ? s[t - o] : 0;
        __syncthreads();
        s[t] += u;
        __syncthreads();
    }
    if (i < n) {
        rowptr[i] = s[t] - v + bbase[blockIdx.x];
        dis[i] = rsqrtf(1.0f + (float)v);
        if (i == n - 1) rowptr[n] = e;
    }
}

// scatter: csr position = rowptr[col] + rank; no atomic dependency
__global__ void k_scat4(const int4* __restrict__ row4, const int4* __restrict__ col4,
                        const int4* __restrict__ pos4, const int* __restrict__ rowptr,
                        int* __restrict__ csr_src, int e4) {
    int i = blockIdx.x * blockDim.x + threadIdx.x;
    if (i >= e4) return;
    int4 r = row4[i];
    int4 c = col4[i];
    int4 p = pos4[i];
    csr_src[rowptr[c.x] + p.x] = r.x;
    csr_src[rowptr[c.y] + p.y] = r.y;
    csr_src[rowptr[c.z] + p.z] = r.z;
    csr_src[rowptr[c.w] + p.w] = r.w;
}

// ---------------- x -> bf16 copy ----------------

__global__ void k_cvt(const float* __restrict__ x, unsigned short* __restrict__ xb,
                      int total4) {
    int i = blockIdx.x * blockDim.x + threadIdx.x;
    if (i >= total4) return;
    float4 v = ((const float4*)x)[i];
    ushort4 o = {(unsigned short)bf16h(v.x), (unsigned short)bf16h(v.y),
                 (unsigned short)bf16h(v.z), (unsigned short)bf16h(v.w)};
    ((ushort4*)xb)[i] = o;
}

// W[k][c] (128x128 f32) x3 -> Wt_hi[c][k], Wt_lo[c][k] (bf16 split); 3 weights fused
__global__ __launch_bounds__(256) void k_wprep3(
        const float* __restrict__ W1, const float* __restrict__ W2,
        const float* __restrict__ W3,
        unsigned short* __restrict__ hi1, unsigned short* __restrict__ lo1,
        unsigned short* __restrict__ hi2, unsigned short* __restrict__ lo2,
        unsigned short* __restrict__ hi3, unsigned short* __restrict__ lo3) {
    int m = blockIdx.x >> 6;               // 64 blocks per matrix
    int i = (blockIdx.x & 63) * 256 + threadIdx.x;  // 16384 per matrix
    const float* W = (m == 0) ? W1 : (m == 1) ? W2 : W3;
    unsigned short* hi = (m == 0) ? hi1 : (m == 1) ? hi2 : hi3;
    unsigned short* lo = (m == 0) ? lo1 : (m == 1) ? lo2 : lo3;
    int k = i >> 7, c = i & 127;
    float w = W[i];
    short h = bf16h(w);
    short l = bf16h(w - bf16f((unsigned short)h));
    hi[c * DIM + k] = (unsigned short)h;
    lo[c * DIM + k] = (unsigned short)l;
}

// ---------------- MFMA matmul, NO bias/relu: Y = A @ W, A bf16 ----------------
// 2-term W split: A@W = A@Wh + A@Wl. LDS-staged A, B-frag reuse.

__global__ __launch_bounds__(256) void k_mm2(
        const unsigned short* __restrict__ A, const unsigned short* __restrict__ wt_hi,
        const unsigned short* __restrict__ wt_lo, unsigned short* __restrict__ out, int n) {
    __shared__ unsigned short sA[64 * SSTR];  // 17408 B
    int tid = threadIdx.x;
    int wave = tid >> 6, lane = tid & 63;
    int r0b = blockIdx.x * 64;

    // ---- stage 64 bf16 A rows (16 KB coalesced) ----
    for (int c = tid; c < 1024; c += 256) {  // 64 rows x 16 chunks of 8 shorts
        int row = c >> 4;
        int cc = (c & 15) * 8;
        int rowg = r0b + row;
        int rowc = rowg < n ? rowg : (n - 1);
        s16x8 v = *(const s16x8*)&A[(size_t)rowc * DIM + cc];
        *(s16x8*)&sA[row * SSTR + cc] = v;
    }
    __syncthreads();

    int lrow = lane & 15;   // A-frag row within tile / C col index
    int lk = lane >> 4;     // k-group 0..3
    bool full = (r0b + 64 <= n);

#pragma unroll
    for (int cti = 0; cti < 2; cti++) {
        int ct = wave * 2 + cti;
        int col = ct * 16 + lrow;
        const unsigned short* bh_base = wt_hi + (size_t)col * DIM + lk * 8;
        const unsigned short* bl_base = wt_lo + (size_t)col * DIM + lk * 8;
        s16x8 bh[4], bl[4];
#pragma unroll
        for (int ks = 0; ks < 4; ks++) {
            bh[ks] = *(const s16x8*)(bh_base + ks * 32);
            bl[ks] = *(const s16x8*)(bl_base + ks * 32);
        }

#pragma unroll
        for (int rt = 0; rt < 4; rt++) {
            const unsigned short* a_base = &sA[(rt * 16 + lrow) * SSTR + lk * 8];
            s16x8 a[4];
#pragma unroll
            for (int ks = 0; ks < 4; ks++) {
                a[ks] = *(const s16x8*)(a_base + ks * 32);
            }
            f32x4 c = {0.f, 0.f, 0.f, 0.f};
#pragma unroll
            for (int ks = 0; ks < 4; ks++) {
                c = __builtin_amdgcn_mfma_f32_16x16x32_bf16(a[ks], bh[ks], c, 0, 0, 0);
                c = __builtin_amdgcn_mfma_f32_16x16x32_bf16(a[ks], bl[ks], c, 0, 0, 0);
            }
            int rbase = r0b + rt * 16 + lk * 4;
            if (full) {
#pragma unroll
                for (int reg = 0; reg < 4; reg++) {
                    out[(size_t)(rbase + reg) * DIM + col] = (unsigned short)bf16h(c[reg]);
                }
            } else {
#pragma unroll
                for (int reg = 0; reg < 4; reg++) {
                    if (rbase + reg < n) {
                        out[(size_t)(rbase + reg) * DIM + col] = (unsigned short)bf16h(c[reg]);
                    }
                }
            }
        }
    }
}

// ---------------- aggregation: 2 nodes per wave, ushort4 lanes ----------------
// lanes 0-31: node 2w, lanes 32-63: node 2w+1; lane owns 4 cols (8B).
// One gather instruction fetches TWO rows (512B). Branchless tail: loop to
// maxlen of the pair; overrun lanes get weight 0 (csr_src padded with zeros,
// so overrun indices still yield a valid node id for address safety).
// h[i] = relu( d_i^2*Y[i] + sum_j d_i*d_j*Y[j] + b )

__global__ __launch_bounds__(256) void k_gcn_agg2(const unsigned short* __restrict__ in,
        const int* __restrict__ csr_src, const int* __restrict__ rowptr,
        const float* __restrict__ dis, const float* __restrict__ bias,
        unsigned short* __restrict__ hout, int n) {
    int wave_id = (blockIdx.x * blockDim.x + threadIdx.x) >> 6;
    if (wave_id * 2 >= n) return;
    int lane = threadIdx.x & 63;
    int half = lane >> 5;
    int c4 = (lane & 31) * 4;             // column base (4 cols, 8B)
    int node = wave_id * 2 + half;
    bool vnode = node < n;
    int nodec = vnode ? node : (n - 1);

    float d = dis[nodec];
    int p0 = rowptr[nodec];
    int len = rowptr[nodec + 1] - p0;
    if (!vnode) len = 0;

    // self term
    ushort4 sv = *(const ushort4*)&in[(size_t)nodec * DIM + c4];
    float dd = d * d;
    float ax = bf16f(sv.x) * dd;
    float ay = bf16f(sv.y) * dd;
    float az = bf16f(sv.z) * dd;
    float aw = bf16f(sv.w) * dd;

    int olen = __shfl_xor(len, 32);
    int maxlen = len > olen ? len : olen;

    int i = 0;
    for (; i + 3 < maxlen; i += 4) {
        int s0 = csr_src[p0 + i];
        int s1 = csr_src[p0 + i + 1];
        int s2 = csr_src[p0 + i + 2];
        int s3 = csr_src[p0 + i + 3];
        float w0 = (i     < len) ? d * dis[s0] : 0.f;
        float w1 = (i + 1 < len) ? d * dis[s1] : 0.f;
        float w2 = (i + 2 < len) ? d * dis[s2] : 0.f;
        float w3 = (i + 3 < len) ? d * dis[s3] : 0.f;
        ushort4 v0 = *(const ushort4*)&in[(size_t)s0 * DIM + c4];
        ushort4 v1 = *(const ushort4*)&in[(size_t)s1 * DIM + c4];
        ushort4 v2 = *(const ushort4*)&in[(size_t)s2 * DIM + c4];
        ushort4 v3 = *(const ushort4*)&in[(size_t)s3 * DIM + c4];
        ax += bf16f(v0.x) * w0; ay += bf16f(v0.y) * w0;
        az += bf16f(v0.z) * w0; aw += bf16f(v0.w) * w0;
        ax += bf16f(v1.x) * w1; ay += bf16f(v1.y) * w1;
        az += bf16f(v1.z) * w1; aw += bf16f(v1.w) * w1;
        ax += bf16f(v2.x) * w2; ay += bf16f(v2.y) * w2;
        az += bf16f(v2.z) * w2; aw += bf16f(v2.w) * w2;
        ax += bf16f(v3.x) * w3; ay += bf16f(v3.y) * w3;
        az += bf16f(v3.z) * w3; aw += bf16f(v3.w) * w3;
    }
    for (; i < maxlen; i++) {
        int s = csr_src[p0 + i];
        float w = (i < len) ? d * dis[s] : 0.f;
        ushort4 v = *(const ushort4*)&in[(size_t)s * DIM + c4];
        ax += bf16f(v.x) * w; ay += bf16f(v.y) * w;
        az += bf16f(v.z) * w; aw += bf16f(v.w) * w;
    }

    if (vnode) {
        float4 bv = *(const float4*)&bias[c4];
        float ox = ax + bv.x, oy = ay + bv.y, oz = az + bv.z, ow = aw + bv.w;
        ox = ox > 0.f ? ox : 0.f;
        oy = oy > 0.f ? oy : 0.f;
        oz = oz > 0.f ? oz : 0.f;
        ow = ow > 0.f ? ow : 0.f;
        ushort4 o = {(unsigned short)bf16h(ox), (unsigned short)bf16h(oy),
                     (unsigned short)bf16h(oz), (unsigned short)bf16h(ow)};
        *(ushort4*)&hout[(size_t)node * DIM + c4] = o;
    }
}

// ---------------- global mean pool: two-phase, device-filling, bf16 input ----------------

__global__ __launch_bounds__(256) void k_pool_part(const unsigned short* __restrict__ h,
        const int* __restrict__ batch, float* __restrict__ part, int n) {
    int g = blockIdx.x >> 4, s = blockIdx.x & 15;
    int lo = 0, hi = n;
    while (lo < hi) { int m = (lo + hi) >> 1; if (batch[m] < g) lo = m + 1; else hi = m; }
    int start = lo;
    int lo2 = start, hi2 = n;
    while (lo2 < hi2) { int m = (lo2 + hi2) >> 1; if (batch[m] < g + 1) lo2 = m + 1; else hi2 = m; }
    int end = lo2;

    int t = threadIdx.x;
    int wave = t >> 6, lane = t & 63;
    float2 acc = {0.f, 0.f};
    for (int r = start + s + 16 * wave; r < end; r += 64) {
        ushort2 v = *(const ushort2*)&h[(size_t)r * DIM + lane * 2];
        acc.x += bf16f(v.x); acc.y += bf16f(v.y);
    }
    __shared__ float2 red[4][64];
    red[wave][lane] = acc;
    __syncthreads();
    if (t < 64) {
        float2 s0 = red[0][t], s1 = red[1][t], s2 = red[2][t], s3 = red[3][t];
        float2 o;
        o.x = s0.x + s1.x + s2.x + s3.x;
        o.y = s0.y + s1.y + s2.y + s3.y;
        *(float2*)&part[(size_t)blockIdx.x * DIM + t * 2] = o;
    }
}

__global__ __launch_bounds__(128) void k_pool_fin(const float* __restrict__ part,
        const int* __restrict__ batch, float* __restrict__ out, int n) {
    int g = blockIdx.x, c = threadIdx.x;
    int lo = 0, hi = n;
    while (lo < hi) { int m = (lo + hi) >> 1; if (batch[m] < g) lo = m + 1; else hi = m; }
    int start = lo;
    int lo2 = start, hi2 = n;
    while (lo2 < hi2) { int m = (lo2 + hi2) >> 1; if (batch[m] < g + 1) lo2 = m + 1; else hi2 = m; }
    int end = lo2;

    float s = 0.f;
#pragma unroll
    for (int k = 0; k < 16; k++) s += part[(size_t)(g * 16 + k) * DIM + c];
    float cnt = (float)(end - start);
    cnt = cnt > 1.f ? cnt : 1.f;
    out[g * DIM + c] = s / cnt;
}

// ---------------- launch ----------------

extern "C" void kernel_launch(void* const* d_in, const int* in_sizes, int n_in,
                              void* d_out, int out_size, void* d_ws, size_t ws_size,
                              hipStream_t stream) {
    const float* x  = (const float*)d_in[0];
    const int*   ei = (const int*)d_in[1];
    const int*   batch = (const int*)d_in[2];
    const float* W1 = (const float*)d_in[3];
    const float* b1 = (const float*)d_in[4];
    const float* W2 = (const float*)d_in[5];
    const float* b2 = (const float*)d_in[6];
    const float* W3 = (const float*)d_in[7];
    const float* b3 = (const float*)d_in[8];

    int n = in_sizes[0] / DIM;  // 50000
    int e = in_sizes[1] / 2;    // 800000
    const int* erow = ei;       // sources
    const int* ecol = ei + e;   // targets
    int e4 = e / 4;             // 200000 (e divisible by 4)
    int nb = (n + 255) / 256;   // 196 scan blocks (<=256 required)

    char* ws = (char*)d_ws;
    size_t off = 0;
    auto alloc = [&](size_t bytes) -> void* {
        void* p = (void*)(ws + off);
        off += (bytes + 255) & ~(size_t)255;
        return p;
    };
    float* dis     = (float*)alloc((size_t)n * 4);
    int*   rowptr  = (int*)alloc((size_t)(n + 1) * 4);
    int*   csr_src = (int*)alloc((size_t)(e + 256) * 4);  // +256 zero pad (overrun reads)
    unsigned short* xb  = (unsigned short*)alloc((size_t)n * DIM * 2);  // x as bf16
    unsigned short* Y   = (unsigned short*)alloc((size_t)n * DIM * 2);  // Y = h@W (bf16)
    unsigned short* hA  = (unsigned short*)alloc((size_t)n * DIM * 2);
    unsigned short* hB  = (unsigned short*)alloc((size_t)n * DIM * 2);
    unsigned short* wt_hi1 = (unsigned short*)alloc(DIM * DIM * 2);
    unsigned short* wt_lo1 = (unsigned short*)alloc(DIM * DIM * 2);
    unsigned short* wt_hi2 = (unsigned short*)alloc(DIM * DIM * 2);
    unsigned short* wt_lo2 = (unsigned short*)alloc(DIM * DIM * 2);
    unsigned short* wt_hi3 = (unsigned short*)alloc(DIM * DIM * 2);
    unsigned short* wt_lo3 = (unsigned short*)alloc(DIM * DIM * 2);
    float* part    = (float*)alloc((size_t)1024 * DIM * 4);  // pool partials
    int*   pos     = (int*)alloc((size_t)e * 4);             // edge ranks
    // transient CSR-build arrays overlap Y (Y first written by mm1, after scat4)
    int* cnt    = (int*)Y;
    int* bsum   = ((int*)Y) + n;
    int* bbase  = ((int*)Y) + n + 256;

    // ---- CSR build (once; edge_index is layer-invariant) ----
    hipMemsetAsync(cnt, 0, (size_t)n * 4, stream);
    hipMemsetAsync(csr_src + e, 0, 256 * 4, stream);  // zero pad -> node 0 (safe)
    k_rank4<<<(e4 + 255) / 256, 256, 0, stream>>>((const int4*)ecol, cnt, (int4*)pos, e4);
    k_bsum<<<nb, 256, 0, stream>>>(cnt, bsum, n);
    k_bscan<<<1, 256, 0, stream>>>(bsum, bbase, nb);
    k_bfinal<<<nb, 256, 0, stream>>>(cnt, bbase, rowptr, dis, n, e);
    k_scat4<<<(e4 + 255) / 256, 256, 0, stream>>>((const int4*)erow, (const int4*)ecol,
                                                  (const int4*)pos, rowptr, csr_src, e4);

    // ---- input cvt + weight prep ----
    int total4 = n * DIM / 4;
    k_cvt<<<(total4 + 255) / 256, 256, 0, stream>>>(x, xb, total4);
    k_wprep3<<<192, 256, 0, stream>>>(W1, W2, W3, wt_hi1, wt_lo1, wt_hi2, wt_lo2,
                                      wt_hi3, wt_lo3);

    int nwaves = (n + 1) / 2;  // 2 nodes per wave
    dim3 aggGrid(((size_t)nwaves * 64 + 255) / 256);
    dim3 mmGrid((n + 63) / 64);

    // layer 1: Y = xb@W1 ; hA = relu(agg(Y) + b1)
    k_mm2<<<mmGrid, 256, 0, stream>>>(xb, wt_hi1, wt_lo1, Y, n);
    k_gcn_agg2<<<aggGrid, 256, 0, stream>>>(Y, csr_src, rowptr, dis, b1, hA, n);
    // layer 2
    k_mm2<<<mmGrid, 256, 0, stream>>>(hA, wt_hi2, wt_lo2, Y, n);
    k_gcn_agg2<<<aggGrid, 256, 0, stream>>>(Y, csr_src, rowptr, dis, b2, hB, n);
    // layer 3
    k_mm2<<<mmGrid, 256, 0, stream>>>(hB, wt_hi3, wt_lo3, Y, n);
    k_gcn_agg2<<<aggGrid, 256, 0, stream>>>(Y, csr_src, rowptr, dis, b3, hA, n);

    // global mean pool (two-phase, batch sorted -> binary-searched ranges)
    k_pool_part<<<1024, 256, 0, stream>>>(hA, batch, part, n);
    k_pool_fin<<<N_GRAPHS, 128, 0, stream>>>(part, batch, (float*)d_out, n);
}

// Round 14
// 254.639 us; speedup vs baseline: 1.1280x; 1.1280x over previous
//
#include <hip/hip_runtime.h>
#include <hip/hip_bf16.h>

#define DIM 128
#define N_GRAPHS 64
#define SSTR 136  // LDS row stride in shorts (272 B)

typedef __attribute__((ext_vector_type(4))) float f32x4;
typedef __attribute__((ext_vector_type(8))) short s16x8;

// ---------------- bf16 helpers (hardware cvt) ----------------

__device__ __forceinline__ short bf16h(float f) {
    return __builtin_bit_cast(short, __float2bfloat16(f));  // HW RTNE cvt
}
__device__ __forceinline__ float bf16f(unsigned short h) {
    unsigned u = ((unsigned)h) << 16;
    return __builtin_bit_cast(float, u);
}

// ---------------- degree / CSR precompute ----------------
// one atomic pass: cnt accumulates degree, returned value is the edge's rank
__global__ void k_rank4(const int4* __restrict__ col4, int* __restrict__ cnt,
                        int4* __restrict__ pos4, int e4) {
    int i = blockIdx.x * blockDim.x + threadIdx.x;
    if (i >= e4) return;
    int4 c = col4[i];
    int4 p;
    p.x = atomicAdd(&cnt[c.x], 1);
    p.y = atomicAdd(&cnt[c.y], 1);
    p.z = atomicAdd(&cnt[c.z], 1);
    p.w = atomicAdd(&cnt[c.w], 1);
    pos4[i] = p;  // coalesced 16B store
}

__global__ __launch_bounds__(256) void k_bsum(const int* __restrict__ cnt,
                                              int* __restrict__ bsum, int n) {
    __shared__ int s[256];
    int t = threadIdx.x;
    int i = blockIdx.x * 256 + t;
    s[t] = (i < n) ? cnt[i] : 0;
    __syncthreads();
    for (int o = 128; o > 0; o >>= 1) {
        if (t < o) s[t] += s[t + o];
        __syncthreads();
    }
    if (t == 0) bsum[blockIdx.x] = s[0];
}

__global__ __launch_bounds__(256) void k_bscan(const int* __restrict__ bsum,
                                               int* __restrict__ bbase, int nb) {
    __shared__ int s[256];
    int t = threadIdx.x;
    int v = (t < nb) ? bsum[t] : 0;
    s[t] = v;
    __syncthreads();
    for (int o = 1; o < 256; o <<= 1) {
        int u = (t >= o) ? s[t - o] : 0;
        __syncthreads();
        s[t] += u;
        __syncthreads();
    }
    if (t < nb) bbase[t] = s[t] - v;  // exclusive
}

// rowptr + dis = rsqrt(1 + degree)
__global__ __launch_bounds__(256) void k_bfinal(const int* __restrict__ cnt,
        const int* __restrict__ bbase, int* __restrict__ rowptr,
        float* __restrict__ dis, int n, int e) {
    __shared__ int s[256];
    int t = threadIdx.x;
    int i = blockIdx.x * 256 + t;
    int v = (i < n) ? cnt[i] : 0;
    s[t] = v;
    __syncthreads();
    for (int o = 1; o < 256; o <<= 1) {
        int u = (t >= o) ? s[t - o] : 0;
        __syncthreads();
        s[t] += u;
        __syncthreads();
    }
    if (i < n) {
        rowptr[i] = s[t] - v + bbase[blockIdx.x];
        dis[i] = rsqrtf(1.0f + (float)v);
        if (i == n - 1) rowptr[n] = e;
    }
}

// scatter: csr position = rowptr[col] + rank; no atomic dependency
__global__ void k_scat4(const int4* __restrict__ row4, const int4* __restrict__ col4,
                        const int4* __restrict__ pos4, const int* __restrict__ rowptr,
                        int* __restrict__ csr_src, int e4) {
    int i = blockIdx.x * blockDim.x + threadIdx.x;
    if (i >= e4) return;
    int4 r = row4[i];
    int4 c = col4[i];
    int4 p = pos4[i];
    csr_src[rowptr[c.x] + p.x] = r.x;
    csr_src[rowptr[c.y] + p.y] = r.y;
    csr_src[rowptr[c.z] + p.z] = r.z;
    csr_src[rowptr[c.w] + p.w] = r.w;
}

// W[k][c] (128x128 f32) x3 -> Wt_hi[c][k], Wt_lo[c][k] (bf16 split); 3 weights fused
__global__ __launch_bounds__(256) void k_wprep3(
        const float* __restrict__ W1, const float* __restrict__ W2,
        const float* __restrict__ W3,
        unsigned short* __restrict__ hi1, unsigned short* __restrict__ lo1,
        unsigned short* __restrict__ hi2, unsigned short* __restrict__ lo2,
        unsigned short* __restrict__ hi3, unsigned short* __restrict__ lo3) {
    int m = blockIdx.x >> 6;               // 64 blocks per matrix
    int i = (blockIdx.x & 63) * 256 + threadIdx.x;  // 16384 per matrix
    const float* W = (m == 0) ? W1 : (m == 1) ? W2 : W3;
    unsigned short* hi = (m == 0) ? hi1 : (m == 1) ? hi2 : hi3;
    unsigned short* lo = (m == 0) ? lo1 : (m == 1) ? lo2 : lo3;
    int k = i >> 7, c = i & 127;
    float w = W[i];
    short h = bf16h(w);
    short l = bf16h(w - bf16f((unsigned short)h));
    hi[c * DIM + k] = (unsigned short)h;
    lo[c * DIM + k] = (unsigned short)l;
}

// ---------------- MFMA matmul core (Y = A @ W, 2-term W split) ----------------
// A staged in LDS as bf16; B-frags (Wh, Wl) in registers, reused over 4 row-tiles.
// mfma_f32_16x16x32_bf16: A row=lane&15, k=(lane>>4)*8+j ; C col=lane&15, row=(lane>>4)*4+reg

__device__ __forceinline__ void mm2_core(
        const unsigned short* sA, const unsigned short* wt_hi,
        const unsigned short* wt_lo, unsigned short* out, int r0b, int n,
        int wave, int lane) {
    int lrow = lane & 15;
    int lk = lane >> 4;
    bool full = (r0b + 64 <= n);

#pragma unroll
    for (int cti = 0; cti < 2; cti++) {
        int ct = wave * 2 + cti;
        int col = ct * 16 + lrow;
        const unsigned short* bh_base = wt_hi + (size_t)col * DIM + lk * 8;
        const unsigned short* bl_base = wt_lo + (size_t)col * DIM + lk * 8;
        s16x8 bh[4], bl[4];
#pragma unroll
        for (int ks = 0; ks < 4; ks++) {
            bh[ks] = *(const s16x8*)(bh_base + ks * 32);
            bl[ks] = *(const s16x8*)(bl_base + ks * 32);
        }

#pragma unroll
        for (int rt = 0; rt < 4; rt++) {
            const unsigned short* a_base = &sA[(rt * 16 + lrow) * SSTR + lk * 8];
            s16x8 a[4];
#pragma unroll
            for (int ks = 0; ks < 4; ks++) {
                a[ks] = *(const s16x8*)(a_base + ks * 32);
            }
            f32x4 c = {0.f, 0.f, 0.f, 0.f};
#pragma unroll
            for (int ks = 0; ks < 4; ks++) {
                c = __builtin_amdgcn_mfma_f32_16x16x32_bf16(a[ks], bh[ks], c, 0, 0, 0);
                c = __builtin_amdgcn_mfma_f32_16x16x32_bf16(a[ks], bl[ks], c, 0, 0, 0);
            }
            int rbase = r0b + rt * 16 + lk * 4;
            if (full) {
#pragma unroll
                for (int reg = 0; reg < 4; reg++) {
                    out[(size_t)(rbase + reg) * DIM + col] = (unsigned short)bf16h(c[reg]);
                }
            } else {
#pragma unroll
                for (int reg = 0; reg < 4; reg++) {
                    if (rbase + reg < n) {
                        out[(size_t)(rbase + reg) * DIM + col] = (unsigned short)bf16h(c[reg]);
                    }
                }
            }
        }
    }
}

// bf16-input mm (layers 2,3)
__global__ __launch_bounds__(256) void k_mm2(
        const unsigned short* __restrict__ A, const unsigned short* __restrict__ wt_hi,
        const unsigned short* __restrict__ wt_lo, unsigned short* __restrict__ out, int n) {
    __shared__ unsigned short sA[64 * SSTR];
    int tid = threadIdx.x;
    int r0b = blockIdx.x * 64;
    for (int c = tid; c < 1024; c += 256) {  // 64 rows x 16 chunks of 8 shorts
        int row = c >> 4;
        int cc = (c & 15) * 8;
        int rowg = r0b + row;
        int rowc = rowg < n ? rowg : (n - 1);
        s16x8 v = *(const s16x8*)&A[(size_t)rowc * DIM + cc];
        *(s16x8*)&sA[row * SSTR + cc] = v;
    }
    __syncthreads();
    mm2_core(sA, wt_hi, wt_lo, out, r0b, n, tid >> 6, tid & 63);
}

// f32-input mm (layer 1): converts x to bf16 during staging (fused k_cvt)
__global__ __launch_bounds__(256) void k_mm2f(
        const float* __restrict__ A, const unsigned short* __restrict__ wt_hi,
        const unsigned short* __restrict__ wt_lo, unsigned short* __restrict__ out, int n) {
    __shared__ unsigned short sA[64 * SSTR];
    int tid = threadIdx.x;
    int r0b = blockIdx.x * 64;
    {
        int subrow = tid >> 5;          // 0..7
        int colb = (tid & 31) * 4;      // element col
        const float4* A4 = (const float4*)A;
#pragma unroll
        for (int j = 0; j < 8; j++) {
            int row = j * 8 + subrow;
            int rowg = r0b + row;
            int rowc = rowg < n ? rowg : (n - 1);
            float4 v = A4[(size_t)rowc * 32 + (colb >> 2)];
            ushort4 hv = {(unsigned short)bf16h(v.x), (unsigned short)bf16h(v.y),
                          (unsigned short)bf16h(v.z), (unsigned short)bf16h(v.w)};
            *(ushort4*)&sA[row * SSTR + colb] = hv;
        }
    }
    __syncthreads();
    mm2_core(sA, wt_hi, wt_lo, out, r0b, n, tid >> 6, tid & 63);
}

// ---------------- aggregation on Y (bf16) + bias + relu -> h (bf16) ----------------
// h[i] = relu( dis_i^2*Y[i] + sum_j dis_i*dis_j*Y[j] + b ); one wave per node.

__global__ __launch_bounds__(256) void k_gcn_agg_bf(const unsigned short* __restrict__ in,
        const int* __restrict__ csr_src, const int* __restrict__ rowptr,
        const float* __restrict__ dis, const float* __restrict__ bias,
        unsigned short* __restrict__ hout, int n) {
    int wid = (blockIdx.x * blockDim.x + threadIdx.x) >> 6;
    if (wid >= n) return;
    int lane = threadIdx.x & 63;
    const int coff = lane * 2;
    float d = dis[wid];
    float dd = d * d;  // self-loop weight
    ushort2 sv = *(const ushort2*)&in[(size_t)wid * DIM + coff];
    float2 acc = {bf16f(sv.x) * dd, bf16f(sv.y) * dd};
    int p = rowptr[wid], p1 = rowptr[wid + 1];
    for (; p + 3 < p1; p += 4) {
        int s0 = csr_src[p], s1 = csr_src[p + 1], s2 = csr_src[p + 2], s3 = csr_src[p + 3];
        float w0 = d * dis[s0], w1 = d * dis[s1], w2 = d * dis[s2], w3 = d * dis[s3];
        ushort2 v0 = *(const ushort2*)&in[(size_t)s0 * DIM + coff];
        ushort2 v1 = *(const ushort2*)&in[(size_t)s1 * DIM + coff];
        ushort2 v2 = *(const ushort2*)&in[(size_t)s2 * DIM + coff];
        ushort2 v3 = *(const ushort2*)&in[(size_t)s3 * DIM + coff];
        acc.x += bf16f(v0.x) * w0; acc.y += bf16f(v0.y) * w0;
        acc.x += bf16f(v1.x) * w1; acc.y += bf16f(v1.y) * w1;
        acc.x += bf16f(v2.x) * w2; acc.y += bf16f(v2.y) * w2;
        acc.x += bf16f(v3.x) * w3; acc.y += bf16f(v3.y) * w3;
    }
    for (; p < p1; p++) {
        int s = csr_src[p];
        float w = d * dis[s];
        ushort2 v = *(const ushort2*)&in[(size_t)s * DIM + coff];
        acc.x += bf16f(v.x) * w;
        acc.y += bf16f(v.y) * w;
    }
    float2 bv = *(const float2*)&bias[coff];
    float ox = acc.x + bv.x;
    float oy = acc.y + bv.y;
    ox = ox > 0.f ? ox : 0.f;
    oy = oy > 0.f ? oy : 0.f;
    ushort2 o = {(unsigned short)bf16h(ox), (unsigned short)bf16h(oy)};
    *(ushort2*)&hout[(size_t)wid * DIM + coff] = o;
}

// ---------------- global mean pool: two-phase, device-filling, bf16 input ----------------

__global__ __launch_bounds__(256) void k_pool_part(const unsigned short* __restrict__ h,
        const int* __restrict__ batch, float* __restrict__ part, int n) {
    int g = blockIdx.x >> 4, s = blockIdx.x & 15;
    int lo = 0, hi = n;
    while (lo < hi) { int m = (lo + hi) >> 1; if (batch[m] < g) lo = m + 1; else hi = m; }
    int start = lo;
    int lo2 = start, hi2 = n;
    while (lo2 < hi2) { int m = (lo2 + hi2) >> 1; if (batch[m] < g + 1) lo2 = m + 1; else hi2 = m; }
    int end = lo2;

    int t = threadIdx.x;
    int wave = t >> 6, lane = t & 63;
    float2 acc = {0.f, 0.f};
    for (int r = start + s + 16 * wave; r < end; r += 64) {
        ushort2 v = *(const ushort2*)&h[(size_t)r * DIM + lane * 2];
        acc.x += bf16f(v.x); acc.y += bf16f(v.y);
    }
    __shared__ float2 red[4][64];
    red[wave][lane] = acc;
    __syncthreads();
    if (t < 64) {
        float2 s0 = red[0][t], s1 = red[1][t], s2 = red[2][t], s3 = red[3][t];
        float2 o;
        o.x = s0.x + s1.x + s2.x + s3.x;
        o.y = s0.y + s1.y + s2.y + s3.y;
        *(float2*)&part[(size_t)blockIdx.x * DIM + t * 2] = o;
    }
}

__global__ __launch_bounds__(128) void k_pool_fin(const float* __restrict__ part,
        const int* __restrict__ batch, float* __restrict__ out, int n) {
    int g = blockIdx.x, c = threadIdx.x;
    int lo = 0, hi = n;
    while (lo < hi) { int m = (lo + hi) >> 1; if (batch[m] < g) lo = m + 1; else hi = m; }
    int start = lo;
    int lo2 = start, hi2 = n;
    while (lo2 < hi2) { int m = (lo2 + hi2) >> 1; if (batch[m] < g + 1) lo2 = m + 1; else hi2 = m; }
    int end = lo2;

    float s = 0.f;
#pragma unroll
    for (int k = 0; k < 16; k++) s += part[(size_t)(g * 16 + k) * DIM + c];
    float cnt = (float)(end - start);
    cnt = cnt > 1.f ? cnt : 1.f;
    out[g * DIM + c] = s / cnt;
}

// ---------------- launch ----------------

extern "C" void kernel_launch(void* const* d_in, const int* in_sizes, int n_in,
                              void* d_out, int out_size, void* d_ws, size_t ws_size,
                              hipStream_t stream) {
    const float* x  = (const float*)d_in[0];
    const int*   ei = (const int*)d_in[1];
    const int*   batch = (const int*)d_in[2];
    const float* W1 = (const float*)d_in[3];
    const float* b1 = (const float*)d_in[4];
    const float* W2 = (const float*)d_in[5];
    const float* b2 = (const float*)d_in[6];
    const float* W3 = (const float*)d_in[7];
    const float* b3 = (const float*)d_in[8];

    int n = in_sizes[0] / DIM;  // 50000
    int e = in_sizes[1] / 2;    // 800000
    const int* erow = ei;       // sources
    const int* ecol = ei + e;   // targets
    int e4 = e / 4;             // 200000 (e divisible by 4)
    int nb = (n + 255) / 256;   // 196 scan blocks (<=256 required)

    char* ws = (char*)d_ws;
    size_t off = 0;
    auto alloc = [&](size_t bytes) -> void* {
        void* p = (void*)(ws + off);
        off += (bytes + 255) & ~(size_t)255;
        return p;
    };
    float* dis     = (float*)alloc((size_t)n * 4);
    int*   rowptr  = (int*)alloc((size_t)(n + 1) * 4);
    int*   csr_src = (int*)alloc((size_t)e * 4);
    unsigned short* Y   = (unsigned short*)alloc((size_t)n * DIM * 2);  // Y = h@W (bf16)
    unsigned short* hA  = (unsigned short*)alloc((size_t)n * DIM * 2);
    unsigned short* hB  = (unsigned short*)alloc((size_t)n * DIM * 2);
    unsigned short* wt_hi1 = (unsigned short*)alloc(DIM * DIM * 2);
    unsigned short* wt_lo1 = (unsigned short*)alloc(DIM * DIM * 2);
    unsigned short* wt_hi2 = (unsigned short*)alloc(DIM * DIM * 2);
    unsigned short* wt_lo2 = (unsigned short*)alloc(DIM * DIM * 2);
    unsigned short* wt_hi3 = (unsigned short*)alloc(DIM * DIM * 2);
    unsigned short* wt_lo3 = (unsigned short*)alloc(DIM * DIM * 2);
    float* part    = (float*)alloc((size_t)1024 * DIM * 4);  // pool partials
    int*   pos     = (int*)alloc((size_t)e * 4);             // edge ranks
    // transient CSR-build arrays overlap Y (Y first written by mm1, after scat4)
    int* cnt    = (int*)Y;
    int* bsum   = ((int*)Y) + n;
    int* bbase  = ((int*)Y) + n + 256;

    // ---- CSR build (once; edge_index is layer-invariant) ----
    hipMemsetAsync(cnt, 0, (size_t)n * 4, stream);
    k_rank4<<<(e4 + 255) / 256, 256, 0, stream>>>((const int4*)ecol, cnt, (int4*)pos, e4);
    k_bsum<<<nb, 256, 0, stream>>>(cnt, bsum, n);
    k_bscan<<<1, 256, 0, stream>>>(bsum, bbase, nb);
    k_bfinal<<<nb, 256, 0, stream>>>(cnt, bbase, rowptr, dis, n, e);
    k_scat4<<<(e4 + 255) / 256, 256, 0, stream>>>((const int4*)erow, (const int4*)ecol,
                                                  (const int4*)pos, rowptr, csr_src, e4);

    // ---- weight prep (transposed bf16 hi/lo, all 3 fused) ----
    k_wprep3<<<192, 256, 0, stream>>>(W1, W2, W3, wt_hi1, wt_lo1, wt_hi2, wt_lo2,
                                      wt_hi3, wt_lo3);

    dim3 aggGrid(((size_t)n * 64 + 255) / 256);
    dim3 mmGrid((n + 63) / 64);

    // layer 1: Y = bf16(x)@W1 (cvt fused into staging) ; hA = relu(agg(Y) + b1)
    k_mm2f<<<mmGrid, 256, 0, stream>>>(x, wt_hi1, wt_lo1, Y, n);
    k_gcn_agg_bf<<<aggGrid, 256, 0, stream>>>(Y, csr_src, rowptr, dis, b1, hA, n);
    // layer 2
    k_mm2<<<mmGrid, 256, 0, stream>>>(hA, wt_hi2, wt_lo2, Y, n);
    k_gcn_agg_bf<<<aggGrid, 256, 0, stream>>>(Y, csr_src, rowptr, dis, b2, hB, n);
    // layer 3
    k_mm2<<<mmGrid, 256, 0, stream>>>(hB, wt_hi3, wt_lo3, Y, n);
    k_gcn_agg_bf<<<aggGrid, 256, 0, stream>>>(Y, csr_src, rowptr, dis, b3, hA, n);

    // global mean pool (two-phase, batch sorted -> binary-searched ranges)
    k_pool_part<<<1024, 256, 0, stream>>>(hA, batch, part, n);
    k_pool_fin<<<N_GRAPHS, 128, 0, stream>>>(part, batch, (float*)d_out, n);
}

// Round 15
// 245.693 us; speedup vs baseline: 1.1691x; 1.0364x over previous
//
#include <hip/hip_runtime.h>
#include <hip/hip_bf16.h>

#define DIM 128
#define N_GRAPHS 64
#define SSTR 136   // LDS row stride in shorts (272 B)
#define MMROWS 128 // rows per mm block: halves per-block weight re-fetch vs 64

typedef __attribute__((ext_vector_type(4))) float f32x4;
typedef __attribute__((ext_vector_type(8))) short s16x8;

// ---------------- bf16 helpers (hardware cvt) ----------------

__device__ __forceinline__ short bf16h(float f) {
    return __builtin_bit_cast(short, __float2bfloat16(f));  // HW RTNE cvt
}
__device__ __forceinline__ float bf16f(unsigned short h) {
    unsigned u = ((unsigned)h) << 16;
    return __builtin_bit_cast(float, u);
}

// ---------------- degree / CSR precompute ----------------
// one atomic pass: cnt accumulates degree, returned value is the edge's rank
__global__ void k_rank4(const int4* __restrict__ col4, int* __restrict__ cnt,
                        int4* __restrict__ pos4, int e4) {
    int i = blockIdx.x * blockDim.x + threadIdx.x;
    if (i >= e4) return;
    int4 c = col4[i];
    int4 p;
    p.x = atomicAdd(&cnt[c.x], 1);
    p.y = atomicAdd(&cnt[c.y], 1);
    p.z = atomicAdd(&cnt[c.z], 1);
    p.w = atomicAdd(&cnt[c.w], 1);
    pos4[i] = p;  // coalesced 16B store
}

__global__ __launch_bounds__(256) void k_bsum(const int* __restrict__ cnt,
                                              int* __restrict__ bsum, int n) {
    __shared__ int s[256];
    int t = threadIdx.x;
    int i = blockIdx.x * 256 + t;
    s[t] = (i < n) ? cnt[i] : 0;
    __syncthreads();
    for (int o = 128; o > 0; o >>= 1) {
        if (t < o) s[t] += s[t + o];
        __syncthreads();
    }
    if (t == 0) bsum[blockIdx.x] = s[0];
}

__global__ __launch_bounds__(256) void k_bscan(const int* __restrict__ bsum,
                                               int* __restrict__ bbase, int nb) {
    __shared__ int s[256];
    int t = threadIdx.x;
    int v = (t < nb) ? bsum[t] : 0;
    s[t] = v;
    __syncthreads();
    for (int o = 1; o < 256; o <<= 1) {
        int u = (t >= o) ? s[t - o] : 0;
        __syncthreads();
        s[t] += u;
        __syncthreads();
    }
    if (t < nb) bbase[t] = s[t] - v;  // exclusive
}

// rowptr + dis = rsqrt(1 + degree)
__global__ __launch_bounds__(256) void k_bfinal(const int* __restrict__ cnt,
        const int* __restrict__ bbase, int* __restrict__ rowptr,
        float* __restrict__ dis, int n, int e) {
    __shared__ int s[256];
    int t = threadIdx.x;
    int i = blockIdx.x * 256 + t;
    int v = (i < n) ? cnt[i] : 0;
    s[t] = v;
    __syncthreads();
    for (int o = 1; o < 256; o <<= 1) {
        int u = (t >= o) ? s[t - o] : 0;
        __syncthreads();
        s[t] += u;
        __syncthreads();
    }
    if (i < n) {
        rowptr[i] = s[t] - v + bbase[blockIdx.x];
        dis[i] = rsqrtf(1.0f + (float)v);
        if (i == n - 1) rowptr[n] = e;
    }
}

// scatter: csr position = rowptr[col] + rank; no atomic dependency
__global__ void k_scat4(const int4* __restrict__ row4, const int4* __restrict__ col4,
                        const int4* __restrict__ pos4, const int* __restrict__ rowptr,
                        int* __restrict__ csr_src, int e4) {
    int i = blockIdx.x * blockDim.x + threadIdx.x;
    if (i >= e4) return;
    int4 r = row4[i];
    int4 c = col4[i];
    int4 p = pos4[i];
    csr_src[rowptr[c.x] + p.x] = r.x;
    csr_src[rowptr[c.y] + p.y] = r.y;
    csr_src[rowptr[c.z] + p.z] = r.z;
    csr_src[rowptr[c.w] + p.w] = r.w;
}

// W[k][c] (128x128 f32) x3 -> Wt_hi[c][k], Wt_lo[c][k] (bf16 split); 3 weights fused
__global__ __launch_bounds__(256) void k_wprep3(
        const float* __restrict__ W1, const float* __restrict__ W2,
        const float* __restrict__ W3,
        unsigned short* __restrict__ hi1, unsigned short* __restrict__ lo1,
        unsigned short* __restrict__ hi2, unsigned short* __restrict__ lo2,
        unsigned short* __restrict__ hi3, unsigned short* __restrict__ lo3) {
    int m = blockIdx.x >> 6;               // 64 blocks per matrix
    int i = (blockIdx.x & 63) * 256 + threadIdx.x;  // 16384 per matrix
    const float* W = (m == 0) ? W1 : (m == 1) ? W2 : W3;
    unsigned short* hi = (m == 0) ? hi1 : (m == 1) ? hi2 : hi3;
    unsigned short* lo = (m == 0) ? lo1 : (m == 1) ? lo2 : lo3;
    int k = i >> 7, c = i & 127;
    float w = W[i];
    short h = bf16h(w);
    short l = bf16h(w - bf16f((unsigned short)h));
    hi[c * DIM + k] = (unsigned short)h;
    lo[c * DIM + k] = (unsigned short)l;
}

// ---------------- MFMA matmul core (Y = A @ W, 2-term W split) ----------------
// 128 rows/block: weights fetched once per 128 rows; B-frags reused over 8 row-tiles.
// mfma_f32_16x16x32_bf16: A row=lane&15, k=(lane>>4)*8+j ; C col=lane&15, row=(lane>>4)*4+reg

__device__ __forceinline__ void mm2_core(
        const unsigned short* sA, const unsigned short* wt_hi,
        const unsigned short* wt_lo, unsigned short* out, int r0b, int n,
        int wave, int lane) {
    int lrow = lane & 15;
    int lk = lane >> 4;
    bool full = (r0b + MMROWS <= n);

#pragma unroll
    for (int cti = 0; cti < 2; cti++) {
        int ct = wave * 2 + cti;
        int col = ct * 16 + lrow;
        const unsigned short* bh_base = wt_hi + (size_t)col * DIM + lk * 8;
        const unsigned short* bl_base = wt_lo + (size_t)col * DIM + lk * 8;
        s16x8 bh[4], bl[4];
#pragma unroll
        for (int ks = 0; ks < 4; ks++) {
            bh[ks] = *(const s16x8*)(bh_base + ks * 32);
            bl[ks] = *(const s16x8*)(bl_base + ks * 32);
        }

#pragma unroll
        for (int rt = 0; rt < MMROWS / 16; rt++) {
            const unsigned short* a_base = &sA[(rt * 16 + lrow) * SSTR + lk * 8];
            s16x8 a[4];
#pragma unroll
            for (int ks = 0; ks < 4; ks++) {
                a[ks] = *(const s16x8*)(a_base + ks * 32);
            }
            f32x4 c = {0.f, 0.f, 0.f, 0.f};
#pragma unroll
            for (int ks = 0; ks < 4; ks++) {
                c = __builtin_amdgcn_mfma_f32_16x16x32_bf16(a[ks], bh[ks], c, 0, 0, 0);
                c = __builtin_amdgcn_mfma_f32_16x16x32_bf16(a[ks], bl[ks], c, 0, 0, 0);
            }
            int rbase = r0b + rt * 16 + lk * 4;
            if (full) {
#pragma unroll
                for (int reg = 0; reg < 4; reg++) {
                    out[(size_t)(rbase + reg) * DIM + col] = (unsigned short)bf16h(c[reg]);
                }
            } else {
#pragma unroll
                for (int reg = 0; reg < 4; reg++) {
                    if (rbase + reg < n) {
                        out[(size_t)(rbase + reg) * DIM + col] = (unsigned short)bf16h(c[reg]);
                    }
                }
            }
        }
    }
}

// bf16-input mm (layers 2,3)
__global__ __launch_bounds__(256) void k_mm2(
        const unsigned short* __restrict__ A, const unsigned short* __restrict__ wt_hi,
        const unsigned short* __restrict__ wt_lo, unsigned short* __restrict__ out, int n) {
    __shared__ unsigned short sA[MMROWS * SSTR];  // 34816 B
    int tid = threadIdx.x;
    int r0b = blockIdx.x * MMROWS;
    for (int c = tid; c < MMROWS * 16; c += 256) {  // rows x 16 chunks of 8 shorts
        int row = c >> 4;
        int cc = (c & 15) * 8;
        int rowg = r0b + row;
        int rowc = rowg < n ? rowg : (n - 1);
        s16x8 v = *(const s16x8*)&A[(size_t)rowc * DIM + cc];
        *(s16x8*)&sA[row * SSTR + cc] = v;
    }
    __syncthreads();
    mm2_core(sA, wt_hi, wt_lo, out, r0b, n, tid >> 6, tid & 63);
}

// f32-input mm (layer 1): converts x to bf16 during staging (fused cvt)
__global__ __launch_bounds__(256) void k_mm2f(
        const float* __restrict__ A, const unsigned short* __restrict__ wt_hi,
        const unsigned short* __restrict__ wt_lo, unsigned short* __restrict__ out, int n) {
    __shared__ unsigned short sA[MMROWS * SSTR];
    int tid = threadIdx.x;
    int r0b = blockIdx.x * MMROWS;
    {
        int subrow = tid >> 5;          // 0..7
        int colb = (tid & 31) * 4;      // element col
        const float4* A4 = (const float4*)A;
#pragma unroll
        for (int j = 0; j < MMROWS / 8; j++) {
            int row = j * 8 + subrow;
            int rowg = r0b + row;
            int rowc = rowg < n ? rowg : (n - 1);
            float4 v = A4[(size_t)rowc * 32 + (colb >> 2)];
            ushort4 hv = {(unsigned short)bf16h(v.x), (unsigned short)bf16h(v.y),
                          (unsigned short)bf16h(v.z), (unsigned short)bf16h(v.w)};
            *(ushort4*)&sA[row * SSTR + colb] = hv;
        }
    }
    __syncthreads();
    mm2_core(sA, wt_hi, wt_lo, out, r0b, n, tid >> 6, tid & 63);
}

// ---------------- aggregation on Y (bf16) + bias + relu -> h (bf16) ----------------
// h[i] = relu( dis_i^2*Y[i] + sum_j dis_i*dis_j*Y[j] + b ); one wave per node.

__global__ __launch_bounds__(256) void k_gcn_agg_bf(const unsigned short* __restrict__ in,
        const int* __restrict__ csr_src, const int* __restrict__ rowptr,
        const float* __restrict__ dis, const float* __restrict__ bias,
        unsigned short* __restrict__ hout, int n) {
    int wid = (blockIdx.x * blockDim.x + threadIdx.x) >> 6;
    if (wid >= n) return;
    int lane = threadIdx.x & 63;
    const int coff = lane * 2;
    float d = dis[wid];
    float dd = d * d;  // self-loop weight
    ushort2 sv = *(const ushort2*)&in[(size_t)wid * DIM + coff];
    float2 acc = {bf16f(sv.x) * dd, bf16f(sv.y) * dd};
    int p = rowptr[wid], p1 = rowptr[wid + 1];
    for (; p + 3 < p1; p += 4) {
        int s0 = csr_src[p], s1 = csr_src[p + 1], s2 = csr_src[p + 2], s3 = csr_src[p + 3];
        float w0 = d * dis[s0], w1 = d * dis[s1], w2 = d * dis[s2], w3 = d * dis[s3];
        ushort2 v0 = *(const ushort2*)&in[(size_t)s0 * DIM + coff];
        ushort2 v1 = *(const ushort2*)&in[(size_t)s1 * DIM + coff];
        ushort2 v2 = *(const ushort2*)&in[(size_t)s2 * DIM + coff];
        ushort2 v3 = *(const ushort2*)&in[(size_t)s3 * DIM + coff];
        acc.x += bf16f(v0.x) * w0; acc.y += bf16f(v0.y) * w0;
        acc.x += bf16f(v1.x) * w1; acc.y += bf16f(v1.y) * w1;
        acc.x += bf16f(v2.x) * w2; acc.y += bf16f(v2.y) * w2;
        acc.x += bf16f(v3.x) * w3; acc.y += bf16f(v3.y) * w3;
    }
    for (; p < p1; p++) {
        int s = csr_src[p];
        float w = d * dis[s];
        ushort2 v = *(const ushort2*)&in[(size_t)s * DIM + coff];
        acc.x += bf16f(v.x) * w;
        acc.y += bf16f(v.y) * w;
    }
    float2 bv = *(const float2*)&bias[coff];
    float ox = acc.x + bv.x;
    float oy = acc.y + bv.y;
    ox = ox > 0.f ? ox : 0.f;
    oy = oy > 0.f ? oy : 0.f;
    ushort2 o = {(unsigned short)bf16h(ox), (unsigned short)bf16h(oy)};
    *(ushort2*)&hout[(size_t)wid * DIM + coff] = o;
}

// ---------------- global mean pool: two-phase, device-filling, bf16 input ----------------

__global__ __launch_bounds__(256) void k_pool_part(const unsigned short* __restrict__ h,
        const int* __restrict__ batch, float* __restrict__ part, int n) {
    int g = blockIdx.x >> 4, s = blockIdx.x & 15;
    int lo = 0, hi = n;
    while (lo < hi) { int m = (lo + hi) >> 1; if (batch[m] < g) lo = m + 1; else hi = m; }
    int start = lo;
    int lo2 = start, hi2 = n;
    while (lo2 < hi2) { int m = (lo2 + hi2) >> 1; if (batch[m] < g + 1) lo2 = m + 1; else hi2 = m; }
    int end = lo2;

    int t = threadIdx.x;
    int wave = t >> 6, lane = t & 63;
    float2 acc = {0.f, 0.f};
    for (int r = start + s + 16 * wave; r < end; r += 64) {
        ushort2 v = *(const ushort2*)&h[(size_t)r * DIM + lane * 2];
        acc.x += bf16f(v.x); acc.y += bf16f(v.y);
    }
    __shared__ float2 red[4][64];
    red[wave][lane] = acc;
    __syncthreads();
    if (t < 64) {
        float2 s0 = red[0][t], s1 = red[1][t], s2 = red[2][t], s3 = red[3][t];
        float2 o;
        o.x = s0.x + s1.x + s2.x + s3.x;
        o.y = s0.y + s1.y + s2.y + s3.y;
        *(float2*)&part[(size_t)blockIdx.x * DIM + t * 2] = o;
    }
}

__global__ __launch_bounds__(128) void k_pool_fin(const float* __restrict__ part,
        const int* __restrict__ batch, float* __restrict__ out, int n) {
    int g = blockIdx.x, c = threadIdx.x;
    int lo = 0, hi = n;
    while (lo < hi) { int m = (lo + hi) >> 1; if (batch[m] < g) lo = m + 1; else hi = m; }
    int start = lo;
    int lo2 = start, hi2 = n;
    while (lo2 < hi2) { int m = (lo2 + hi2) >> 1; if (batch[m] < g + 1) lo2 = m + 1; else hi2 = m; }
    int end = lo2;

    float s = 0.f;
#pragma unroll
    for (int k = 0; k < 16; k++) s += part[(size_t)(g * 16 + k) * DIM + c];
    float cnt = (float)(end - start);
    cnt = cnt > 1.f ? cnt : 1.f;
    out[g * DIM + c] = s / cnt;
}

// ---------------- launch ----------------

extern "C" void kernel_launch(void* const* d_in, const int* in_sizes, int n_in,
                              void* d_out, int out_size, void* d_ws, size_t ws_size,
                              hipStream_t stream) {
    const float* x  = (const float*)d_in[0];
    const int*   ei = (const int*)d_in[1];
    const int*   batch = (const int*)d_in[2];
    const float* W1 = (const float*)d_in[3];
    const float* b1 = (const float*)d_in[4];
    const float* W2 = (const float*)d_in[5];
    const float* b2 = (const float*)d_in[6];
    const float* W3 = (const float*)d_in[7];
    const float* b3 = (const float*)d_in[8];

    int n = in_sizes[0] / DIM;  // 50000
    int e = in_sizes[1] / 2;    // 800000
    const int* erow = ei;       // sources
    const int* ecol = ei + e;   // targets
    int e4 = e / 4;             // 200000 (e divisible by 4)
    int nb = (n + 255) / 256;   // 196 scan blocks (<=256 required)

    char* ws = (char*)d_ws;
    size_t off = 0;
    auto alloc = [&](size_t bytes) -> void* {
        void* p = (void*)(ws + off);
        off += (bytes + 255) & ~(size_t)255;
        return p;
    };
    float* dis     = (float*)alloc((size_t)n * 4);
    int*   rowptr  = (int*)alloc((size_t)(n + 1) * 4);
    int*   csr_src = (int*)alloc((size_t)e * 4);
    unsigned short* Y   = (unsigned short*)alloc((size_t)n * DIM * 2);  // Y = h@W (bf16)
    unsigned short* hA  = (unsigned short*)alloc((size_t)n * DIM * 2);
    unsigned short* hB  = (unsigned short*)alloc((size_t)n * DIM * 2);
    unsigned short* wt_hi1 = (unsigned short*)alloc(DIM * DIM * 2);
    unsigned short* wt_lo1 = (unsigned short*)alloc(DIM * DIM * 2);
    unsigned short* wt_hi2 = (unsigned short*)alloc(DIM * DIM * 2);
    unsigned short* wt_lo2 = (unsigned short*)alloc(DIM * DIM * 2);
    unsigned short* wt_hi3 = (unsigned short*)alloc(DIM * DIM * 2);
    unsigned short* wt_lo3 = (unsigned short*)alloc(DIM * DIM * 2);
    float* part    = (float*)alloc((size_t)1024 * DIM * 4);  // pool partials
    int*   pos     = (int*)alloc((size_t)e * 4);             // edge ranks
    // transient CSR-build arrays overlap Y (Y first written by mm1, after scat4)
    int* cnt    = (int*)Y;
    int* bsum   = ((int*)Y) + n;
    int* bbase  = ((int*)Y) + n + 256;

    // ---- CSR build (once; edge_index is layer-invariant) ----
    hipMemsetAsync(cnt, 0, (size_t)n * 4, stream);
    k_rank4<<<(e4 + 255) / 256, 256, 0, stream>>>((const int4*)ecol, cnt, (int4*)pos, e4);
    k_bsum<<<nb, 256, 0, stream>>>(cnt, bsum, n);
    k_bscan<<<1, 256, 0, stream>>>(bsum, bbase, nb);
    k_bfinal<<<nb, 256, 0, stream>>>(cnt, bbase, rowptr, dis, n, e);
    k_scat4<<<(e4 + 255) / 256, 256, 0, stream>>>((const int4*)erow, (const int4*)ecol,
                                                  (const int4*)pos, rowptr, csr_src, e4);

    // ---- weight prep (transposed bf16 hi/lo, all 3 fused) ----
    k_wprep3<<<192, 256, 0, stream>>>(W1, W2, W3, wt_hi1, wt_lo1, wt_hi2, wt_lo2,
                                      wt_hi3, wt_lo3);

    dim3 aggGrid(((size_t)n * 64 + 255) / 256);
    dim3 mmGrid((n + MMROWS - 1) / MMROWS);

    // layer 1: Y = bf16(x)@W1 (cvt fused into staging) ; hA = relu(agg(Y) + b1)
    k_mm2f<<<mmGrid, 256, 0, stream>>>(x, wt_hi1, wt_lo1, Y, n);
    k_gcn_agg_bf<<<aggGrid, 256, 0, stream>>>(Y, csr_src, rowptr, dis, b1, hA, n);
    // layer 2
    k_mm2<<<mmGrid, 256, 0, stream>>>(hA, wt_hi2, wt_lo2, Y, n);
    k_gcn_agg_bf<<<aggGrid, 256, 0, stream>>>(Y, csr_src, rowptr, dis, b2, hB, n);
    // layer 3
    k_mm2<<<mmGrid, 256, 0, stream>>>(hB, wt_hi3, wt_lo3, Y, n);
    k_gcn_agg_bf<<<aggGrid, 256, 0, stream>>>(Y, csr_src, rowptr, dis, b3, hA, n);

    // global mean pool (two-phase, batch sorted -> binary-searched ranges)
    k_pool_part<<<1024, 256, 0, stream>>>(hA, batch, part, n);
    k_pool_fin<<<N_GRAPHS, 128, 0, stream>>>(part, batch, (float*)d_out, n);
}